// Round 1
// baseline (371.789 us; speedup 1.0000x reference)
//
#include <hip/hip_runtime.h>

// EdgeConv with KNN graph: B=8, N=4096, D=3, E=64, K=32.
// out[b,i,e] = max_{j in knn32(i)} theta[:,e]·(x_j - x_i) + theta_b[e]
//              + phi[:,e]·x_i + phi_b[e]
//
// One wave per point i. Batch's 4096 points staged in LDS. Each lane holds 64
// candidate distance keys in registers; exact top-32 via 2-pass 8-bit radix
// select (histograms in LDS) + (key,index) tie-break in the boundary sub-bin,
// matching jax.lax.top_k's lower-index-first tie semantics.

#define NPTS 4096
#define KNN  32

__global__ __launch_bounds__(256, 3)
void edgeconv_knn_kernel(const float* __restrict__ x,
                         const float* __restrict__ theta_w,
                         const float* __restrict__ theta_b,
                         const float* __restrict__ phi_w,
                         const float* __restrict__ phi_b,
                         float* __restrict__ out)
{
    __shared__ float2 s_xy[NPTS];          // 32 KB
    __shared__ float  s_z[NPTS];           // 16 KB
    __shared__ unsigned int s_scr[4][256]; // 4 KB: per-wave hist, reused as sub/sel/cnt

    const int tid  = threadIdx.x;
    const int wave = tid >> 6;
    const int lane = tid & 63;

    const int b  = blockIdx.x >> 8;          // 256 WGs per batch
    const int i0 = (blockIdx.x & 255) << 4;  // 16 points per WG

    // per-lane output-channel constants (lane == channel e), coalesced loads
    const float tw0 = theta_w[lane];
    const float tw1 = theta_w[64 + lane];
    const float tw2 = theta_w[128 + lane];
    const float tbv = theta_b[lane];
    const float pw0 = phi_w[lane];
    const float pw1 = phi_w[64 + lane];
    const float pw2 = phi_w[128 + lane];
    const float pbv = phi_b[lane];

    // ---- stage batch points into LDS ----
    const float* xb = x + (size_t)b * NPTS * 3;
    for (int p = tid; p < NPTS; p += 256) {
        float px = xb[p * 3 + 0];
        float py = xb[p * 3 + 1];
        float pz = xb[p * 3 + 2];
        s_xy[p] = make_float2(px, py);
        s_z[p]  = pz;
    }
    __syncthreads();

    unsigned int* hist = s_scr[wave];         // [256] during radix passes
    unsigned int* subk = s_scr[wave];         // [64]  after passes (aliased, safe)
    unsigned int* subj = s_scr[wave] + 64;    // [64]
    unsigned int* sel  = s_scr[wave] + 128;   // [32]
    unsigned int* cnt  = s_scr[wave] + 160;   // [2]: 0=sel count, 1=sub count

    // wave-cooperative: find first bin with inclusive-cum >= target over 256 bins
    auto scan_find = [&](unsigned int target, unsigned int& bin, unsigned int& before) {
        unsigned int h0 = hist[lane * 4 + 0];
        unsigned int h1 = hist[lane * 4 + 1];
        unsigned int h2 = hist[lane * 4 + 2];
        unsigned int h3 = hist[lane * 4 + 3];
        unsigned int lsum = h0 + h1 + h2 + h3;
        unsigned int pre = lsum;
        #pragma unroll
        for (int off = 1; off < 64; off <<= 1) {
            unsigned int t = __shfl_up(pre, off, 64);
            if (lane >= off) pre += t;
        }
        unsigned int excl = pre - lsum;            // keys in bins < 4*lane
        unsigned int c0 = excl + h0, c1 = c0 + h1, c2 = c1 + h2, c3 = c2 + h3;
        unsigned int pack = 0xFFFFFFFFu;           // (bin<<13)|before ; before<=4096
        if (c3 >= target) pack = (((unsigned)(lane * 4 + 3)) << 13) | c2;
        if (c2 >= target) pack = (((unsigned)(lane * 4 + 2)) << 13) | c1;
        if (c1 >= target) pack = (((unsigned)(lane * 4 + 1)) << 13) | c0;
        if (c0 >= target) pack = (((unsigned)(lane * 4 + 0)) << 13) | excl;
        #pragma unroll
        for (int off = 32; off >= 1; off >>= 1)
            pack = min(pack, (unsigned int)__shfl_xor(pack, off, 64));
        bin = pack >> 13;
        before = pack & 0x1FFFu;
    };

    for (int r = 0; r < 4; ++r) {
        const int i = i0 + wave * 4 + r;
        const float2 pxy = s_xy[i];
        const float  pz  = s_z[i];
        // same fmaf chain as per-candidate sq -> self-dist is exactly 0
        const float sqi = fmaf(pz, pz, fmaf(pxy.y, pxy.y, pxy.x * pxy.x));

        // ---- phase A: distances for candidates j = s*64+lane, keys in regs ----
        unsigned int key[64];
        #pragma unroll
        for (int s = 0; s < 64; ++s) {
            const int j = (s << 6) + lane;
            const float2 q  = s_xy[j];
            const float  qz = s_z[j];
            const float sqj = fmaf(qz, qz, fmaf(q.y, q.y, q.x * q.x));
            const float dt  = fmaf(pz, qz, fmaf(pxy.y, q.y, pxy.x * q.x));
            float dist = (sqi + sqj) - 2.0f * dt;      // reference formula
            dist = fmaxf(dist, 0.0f);                  // nonneg -> uint-order == float-order
            key[s] = __float_as_uint(dist);
        }
        __syncthreads();

        // ---- radix pass 1: exponent byte (key >> 23) ----
        hist[lane] = 0; hist[lane + 64] = 0; hist[lane + 128] = 0; hist[lane + 192] = 0;
        __syncthreads();
        #pragma unroll
        for (int s = 0; s < 64; ++s) atomicAdd(&hist[key[s] >> 23], 1u);
        __syncthreads();

        unsigned int B1, before1;
        scan_find(KNN, B1, before1);          // before1 < 32
        const unsigned int need1 = KNN - before1;
        __syncthreads();

        // ---- radix pass 2: mantissa bits [22:15], restricted to bin B1 ----
        hist[lane] = 0; hist[lane + 64] = 0; hist[lane + 128] = 0; hist[lane + 192] = 0;
        __syncthreads();
        #pragma unroll
        for (int s = 0; s < 64; ++s)
            if ((key[s] >> 23) == B1) atomicAdd(&hist[(key[s] >> 15) & 0xFFu], 1u);
        __syncthreads();

        unsigned int B2, before2;
        scan_find(need1, B2, before2);
        const unsigned int need2  = need1 - before2;       // 1..32
        const unsigned int prefix = (B1 << 8) | B2;        // == (selected key >> 15)
        __syncthreads();

        // ---- collect: strict-below -> sel, boundary sub-bin -> sub list ----
        if (lane < 2)   cnt[lane] = 0;
        if (lane < KNN) sel[lane] = (unsigned int)i;       // safe prefill (self)
        __syncthreads();
        #pragma unroll
        for (int s = 0; s < 64; ++s) {
            const unsigned int kp = key[s] >> 15;
            const unsigned int j  = (unsigned int)((s << 6) + lane);
            if (kp < prefix) {
                unsigned int idx = atomicAdd(&cnt[0], 1u);
                if (idx < KNN) sel[idx] = j;               // count == 32-need2 by construction
            } else if (kp == prefix) {
                unsigned int idx = atomicAdd(&cnt[1], 1u);
                if (idx < 64) { subk[idx] = key[s]; subj[idx] = j; }
            }
        }
        __syncthreads();

        // ---- tie-break within sub-bin: rank by (full key, index), take need2 ----
        unsigned int m = cnt[1];
        if (m > 64) m = 64;
        if ((unsigned int)lane < m) {
            const unsigned int myk = subk[lane];
            const unsigned int myj = subj[lane];
            unsigned int rank = 0;
            for (unsigned int u = 0; u < m; ++u) {
                const unsigned int k2 = subk[u];
                const unsigned int j2 = subj[u];
                rank += (k2 < myk) || (k2 == myk && j2 < myj);
            }
            if (rank < need2) {
                unsigned int idx = atomicAdd(&cnt[0], 1u);
                if (idx < KNN) sel[idx] = myj;
            }
        }
        __syncthreads();

        // ---- epilogue: lane = channel e; max over 32 selected neighbors ----
        const float basev = tbv + pbv + fmaf(pw2, pz, fmaf(pw1, pxy.y, pw0 * pxy.x));
        float mx = -3.0e38f;
        #pragma unroll
        for (int t = 0; t < KNN; ++t) {
            const unsigned int j = sel[t];                 // uniform -> LDS broadcast
            const float2 q  = s_xy[j];
            const float  qz = s_z[j];
            const float dx = q.x - pxy.x;
            const float dy = q.y - pxy.y;
            const float dz = qz  - pz;
            const float proj = fmaf(tw2, dz, fmaf(tw1, dy, tw0 * dx));
            mx = fmaxf(mx, proj);
        }
        out[(((size_t)b * NPTS + (size_t)i) << 6) + lane] = mx + basev;
        __syncthreads();
    }
}

extern "C" void kernel_launch(void* const* d_in, const int* in_sizes, int n_in,
                              void* d_out, int out_size, void* d_ws, size_t ws_size,
                              hipStream_t stream) {
    const float* x  = (const float*)d_in[0];
    const float* tw = (const float*)d_in[1];
    const float* tb = (const float*)d_in[2];
    const float* pw = (const float*)d_in[3];
    const float* pb = (const float*)d_in[4];
    float* out = (float*)d_out;

    dim3 grid(8 * (NPTS / 16));   // 2048 WGs: 256 per batch, 16 points each
    dim3 block(256);
    hipLaunchKernelGGL(edgeconv_knn_kernel, grid, block, 0, stream,
                       x, tw, tb, pw, pb, out);
}

// Round 2
// 232.946 us; speedup vs baseline: 1.5960x; 1.5960x over previous
//
#include <hip/hip_runtime.h>

// EdgeConv with KNN graph: B=8, N=4096, D=3, E=64, K=32.
// One wave per point. Batch staged in LDS (52 KB). Per lane: 64 candidate
// distance keys in registers. Exact top-32 via:
//   1) wave-uniform threshold search (count-below + gallop + binary refine)
//      until candidate pool <= 64,
//   2) pool compaction to one entry per lane,
//   3) 64-lane bitonic sort by (key, idx) -> lanes 0..31 hold the K nearest
//      with jax.lax.top_k's lower-index tie-break.
// No histograms, no in-loop __syncthreads (all select state is wave-private).

#define NPTS 4096
#define KNN  32

#define WFENCE() __asm__ volatile("s_waitcnt lgkmcnt(0)" ::: "memory")

__global__ __launch_bounds__(512, 6)
void edgeconv_knn_kernel(const float* __restrict__ x,
                         const float* __restrict__ theta_w,
                         const float* __restrict__ theta_b,
                         const float* __restrict__ phi_w,
                         const float* __restrict__ phi_b,
                         float* __restrict__ out)
{
    __shared__ float2 s_xy[NPTS];              // 32 KB
    __shared__ float  s_z[NPTS];               // 16 KB
    __shared__ unsigned int s_poolk[8][64];    // 2 KB  per-wave pool keys
    __shared__ unsigned int s_pooli[8][64];    // 2 KB  per-wave pool indices
    __shared__ unsigned int s_cnt[8];          // 32 B

    const int tid  = threadIdx.x;
    const int wv   = tid >> 6;
    const int lane = tid & 63;

    const int b  = blockIdx.x >> 7;            // 128 WGs per batch
    const int i0 = (blockIdx.x & 127) << 5;    // 32 points per WG

    // lane == output channel e
    const float tw0 = theta_w[lane];
    const float tw1 = theta_w[64 + lane];
    const float tw2 = theta_w[128 + lane];
    const float tbv = theta_b[lane];
    const float pw0 = phi_w[lane];
    const float pw1 = phi_w[64 + lane];
    const float pw2 = phi_w[128 + lane];
    const float pbv = phi_b[lane];

    const float* xb = x + (size_t)b * NPTS * 3;
    for (int p = tid; p < NPTS; p += 512) {
        float px = xb[p * 3 + 0];
        float py = xb[p * 3 + 1];
        float pz = xb[p * 3 + 2];
        s_xy[p] = make_float2(px, py);
        s_z[p]  = pz;
    }
    __syncthreads();

    for (int r = 0; r < 4; ++r) {
        const int i = i0 + wv * 4 + r;
        const float2 pxy = s_xy[i];
        const float  pz  = s_z[i];
        const float sqi = fmaf(pz, pz, fmaf(pxy.y, pxy.y, pxy.x * pxy.x));

        // ---- phase A: 64 distance keys per lane, j = s*64+lane ----
        unsigned int key[64];
        #pragma unroll
        for (int s = 0; s < 64; ++s) {
            const int j = (s << 6) + lane;
            const float2 q  = s_xy[j];
            const float  qz = s_z[j];
            const float sqj = fmaf(qz, qz, fmaf(q.y, q.y, q.x * q.x));
            const float dt  = fmaf(pz, qz, fmaf(pxy.y, q.y, pxy.x * q.x));
            float dist = (sqi + sqj) - 2.0f * dt;
            dist = fmaxf(dist, 0.0f);
            key[s] = __float_as_uint(dist);
        }

        // ---- min nonzero key (wave-uniform after reduce) ----
        unsigned int mn = 0xFFFFFFFFu;
        #pragma unroll
        for (int s = 0; s < 64; ++s) {
            const unsigned int k2 = key[s];
            if (k2 != 0u) mn = min(mn, k2);
        }
        #pragma unroll
        for (int off = 1; off < 64; off <<= 1)
            mn = min(mn, (unsigned int)__shfl_xor((int)mn, off, 64));

        // count of keys strictly below T (wave total)
        auto cnt_lt = [&](unsigned int T) -> unsigned int {
            unsigned int c = 0;
            #pragma unroll
            for (int s = 0; s < 64; ++s) c += (key[s] < T) ? 1u : 0u;
            #pragma unroll
            for (int off = 1; off < 64; off <<= 1)
                c += (unsigned int)__shfl_xor((int)c, off, 64);
            return c;
        };

        // ---- gallop up by octaves (accelerating) until count >= K ----
        unsigned int L = mn & 0xFF800000u;           // below L: only zero keys
        unsigned int H = L;
        unsigned int stepOct = 1u << 23;
        unsigned int c;
        do {
            unsigned int Hn = H + stepOct;
            if (Hn > 0x7F800000u || Hn < H) Hn = 0x7F800000u;
            L = H; H = Hn;
            stepOct <<= 1;
            c = cnt_lt(H);
        } while (c < KNN);

        // ---- binary refine until pool fits in 64 lanes ----
        while (c > 64u && (H - L) > 1u) {
            const unsigned int M = L + ((H - L) >> 1);
            const unsigned int cm = cnt_lt(M);
            if (cm >= KNN) { H = M; c = cm; } else { L = M; }
        }

        // ---- pool build: all keys < H, appended to per-wave LDS pool ----
        if (lane == 0) s_cnt[wv] = 0u;
        WFENCE();
        #pragma unroll
        for (int s = 0; s < 64; ++s) {
            if (key[s] < H) {
                const unsigned int p = atomicAdd(&s_cnt[wv], 1u);
                if (p < 64u) {
                    s_poolk[wv][p] = key[s];
                    s_pooli[wv][p] = (unsigned int)((s << 6) + lane);
                }
            }
        }
        WFENCE();
        unsigned int m = s_cnt[wv];
        if (m > 64u) m = 64u;

        unsigned int myk, myj;
        if ((unsigned int)lane < m) {
            myk = s_poolk[wv][lane];
            myj = s_pooli[wv][lane];
        } else {
            myk = 0xFFFFFFFFu;
            myj = (unsigned int)(NPTS + lane);   // unique, sorts last
        }

        // ---- 64-lane bitonic sort ascending by (key, idx) ----
        #pragma unroll
        for (int k = 2; k <= 64; k <<= 1) {
            #pragma unroll
            for (int jj = k >> 1; jj >= 1; jj >>= 1) {
                const unsigned int ok = (unsigned int)__shfl_xor((int)myk, jj, 64);
                const unsigned int oj = (unsigned int)__shfl_xor((int)myj, jj, 64);
                const bool up      = ((lane & k) == 0);
                const bool first   = ((lane & jj) == 0);
                const bool wantmin = (first == up);
                const bool less    = (myk < ok) || (myk == ok && myj < oj);
                if (less != wantmin) { myk = ok; myj = oj; }
            }
        }
        // lanes 0..31 now hold the 32 nearest neighbors' indices in myj

        // ---- neighbor deltas in registers (lanes 0..31), broadcast via readlane
        float dx = 0.f, dy = 0.f, dz = 0.f;
        if (lane < KNN) {
            const float2 q  = s_xy[myj];
            const float  qz = s_z[myj];
            dx = q.x - pxy.x;
            dy = q.y - pxy.y;
            dz = qz  - pz;
        }

        const float basev = tbv + pbv + fmaf(pw2, pz, fmaf(pw1, pxy.y, pw0 * pxy.x));
        float mx = -3.0e38f;
        #pragma unroll
        for (int t = 0; t < KNN; ++t) {
            const float ndx = __builtin_bit_cast(float, __builtin_amdgcn_readlane(__builtin_bit_cast(int, dx), t));
            const float ndy = __builtin_bit_cast(float, __builtin_amdgcn_readlane(__builtin_bit_cast(int, dy), t));
            const float ndz = __builtin_bit_cast(float, __builtin_amdgcn_readlane(__builtin_bit_cast(int, dz), t));
            const float proj = fmaf(tw2, ndz, fmaf(tw1, ndy, tw0 * ndx));
            mx = fmaxf(mx, proj);
        }
        out[(((size_t)b * NPTS + (size_t)i) << 6) + lane] = mx + basev;
        WFENCE();   // pool LDS reuse next r-iteration (wave-local ordering)
    }
}

extern "C" void kernel_launch(void* const* d_in, const int* in_sizes, int n_in,
                              void* d_out, int out_size, void* d_ws, size_t ws_size,
                              hipStream_t stream) {
    const float* x  = (const float*)d_in[0];
    const float* tw = (const float*)d_in[1];
    const float* tb = (const float*)d_in[2];
    const float* pw = (const float*)d_in[3];
    const float* pb = (const float*)d_in[4];
    float* out = (float*)d_out;

    dim3 grid(8 * (NPTS / 32));   // 1024 WGs: 128 per batch, 32 points each
    dim3 block(512);
    hipLaunchKernelGGL(edgeconv_knn_kernel, grid, block, 0, stream,
                       x, tw, tb, pw, pb, out);
}